// Round 5
// baseline (884.989 us; speedup 1.0000x reference)
//
#include <hip/hip_runtime.h>

// STATE=4096, CDIM=1024, fan_in=5121. RK4 x 4 steps = 16 aug-dynamics evals,
// each eval = 4 sequential matvecs. Weights: state rows transposed to
// column-major bf16 Wt[col][row] in ws; c-rows' contribution + bias in fp32
// (cp1/cp2); t-row exact fp32 (T1/T2).
// Phase kernel: 4 cols/block, weights DMA'd global->LDS via
// __builtin_amdgcn_global_load_lds (width 16) for deep in-flight (32KB/block,
// 4 blocks/CU = 128KB/CU), x held in VGPRs (split-K per wave), shuffle
// reduce, 4-lane epilogue builds next phase's x vector.
#define N      4096
#define NC     1024
#define STEPS  4
#define TPB    256

typedef unsigned short us8 __attribute__((ext_vector_type(8)));

__device__ __forceinline__ float bf2f(unsigned short u) {
  union { unsigned int i; float f; } v; v.i = ((unsigned int)u) << 16; return v.f;
}
__device__ __forceinline__ unsigned short f2bf(float f) {
  union { float f; unsigned int i; } v; v.f = f;
  const unsigned int u = v.i;
  return (unsigned short)((u + 0x7FFFu + ((u >> 16) & 1u)) >> 16);  // RNE
}
__device__ __forceinline__ float sigf(float x) { return 1.0f / (1.0f + __expf(-x)); }

// Async global->LDS DMA, 16 B per lane. LDS dest = base + lane*16 (base must
// be wave-uniform); global addr is per-lane.
__device__ __forceinline__ void load16(const unsigned short* g, unsigned short* l) {
  __builtin_amdgcn_global_load_lds(
      (__attribute__((address_space(1))) void*)(g),
      (__attribute__((address_space(3))) void*)(l),
      16, 0, 0);
}

// ---------------------------------------------------------------------------
// init: ycur=h, cp=bias, xA=sig(h), T=t-row (fp32 exact), rk=0
// ---------------------------------------------------------------------------
__global__ __launch_bounds__(TPB) void k_init(const float* __restrict__ h,
                                              const float* __restrict__ W1,
                                              const float* __restrict__ W2,
                                              const float* __restrict__ b1,
                                              const float* __restrict__ b2,
                                              float* __restrict__ ycur,
                                              float* __restrict__ cp1,
                                              float* __restrict__ cp2,
                                              float* __restrict__ xA,
                                              float* __restrict__ T1,
                                              float* __restrict__ T2,
                                              float* __restrict__ rk) {
  const int j = blockIdx.x * TPB + threadIdx.x;
  if (j < N) {
    ycur[j] = h[j];
    cp1[j] = b1[j];
    cp2[j] = b2[j];
    xA[j] = sigf(h[j]);
    T1[j] = W1[(size_t)(NC + N) * N + j];   // row 5120 (t-row)
    T2[j] = W2[(size_t)(NC + N) * N + j];
  }
  if (j < 16) rk[j] = 0.f;
}

// ---------------------------------------------------------------------------
// Transpose+convert: W state rows [NC, NC+N) fp32 row-major -> Wt[col][row]
// bf16. 64x64 LDS tiles; us8 (16B) stores: 8 consecutive rows of one column
// per lane -> 128B runs per 8 lanes (8x better than 2B/lane). grid (64,64,2).
// ---------------------------------------------------------------------------
__global__ __launch_bounds__(TPB) void k_conv(const float* __restrict__ W1,
                                              const float* __restrict__ W2,
                                              unsigned short* __restrict__ Wt1,
                                              unsigned short* __restrict__ Wt2) {
  __shared__ float tile[64][65];
  const float* __restrict__ W = blockIdx.z ? W2 : W1;
  unsigned short* __restrict__ Wt = blockIdx.z ? Wt2 : Wt1;
  const int i0 = blockIdx.x * 64;   // state-row offset
  const int j0 = blockIdx.y * 64;   // column offset
  const int c = threadIdx.x & 63, rq = threadIdx.x >> 6;
#pragma unroll
  for (int m = 0; m < 16; ++m) {
    const int ii = (m << 2) + rq;
    tile[ii][c] = W[(size_t)(NC + i0 + ii) * N + j0 + c];
  }
  __syncthreads();
#pragma unroll
  for (int it = 0; it < 2; ++it) {
    const int lin = it * 256 + threadIdx.x;
    const int jj = lin >> 3, g = lin & 7;
    us8 o;
#pragma unroll
    for (int e = 0; e < 8; ++e) o[e] = f2bf(tile[g * 8 + e][jj]);
    *reinterpret_cast<us8*>(&Wt[(size_t)(j0 + jj) * N + i0 + g * 8]) = o;
  }
}

// ---------------------------------------------------------------------------
// cp += c @ W[0:NC]  (fp32, once). grid (16, 8, 2), block 256.
// ---------------------------------------------------------------------------
__global__ __launch_bounds__(TPB) void k_cpart(const float* __restrict__ W1,
                                               const float* __restrict__ W2,
                                               const float* __restrict__ c,
                                               float* __restrict__ cp1,
                                               float* __restrict__ cp2) {
  const float* __restrict__ W = blockIdx.z ? W2 : W1;
  float* __restrict__ cp = blockIdx.z ? cp2 : cp1;
  __shared__ float xs[128];
  __shared__ float red[8][256];
  const int tid = threadIdx.x;
  const int cb = blockIdx.x, rc = blockIdx.y;
  const int r0 = rc * 128;
  if (tid < 128) xs[tid] = c[r0 + tid];
  __syncthreads();
  const int cg = tid & 31, rg = tid >> 5;
  const float* __restrict__ wbase = W + (size_t)r0 * N + cb * 256 + cg * 8;
  float a[8] = {0,0,0,0,0,0,0,0};
#pragma unroll
  for (int k = 0; k < 16; ++k) {
    const int r = rg + (k << 3);
    const float xv = xs[r];
    const float4 wa = *reinterpret_cast<const float4*>(wbase + (size_t)r * N);
    const float4 wb = *reinterpret_cast<const float4*>(wbase + (size_t)r * N + 4);
    a[0] = fmaf(wa.x, xv, a[0]); a[1] = fmaf(wa.y, xv, a[1]);
    a[2] = fmaf(wa.z, xv, a[2]); a[3] = fmaf(wa.w, xv, a[3]);
    a[4] = fmaf(wb.x, xv, a[4]); a[5] = fmaf(wb.y, xv, a[5]);
    a[6] = fmaf(wb.z, xv, a[6]); a[7] = fmaf(wb.w, xv, a[7]);
  }
#pragma unroll
  for (int e = 0; e < 8; ++e) red[rg][cg * 8 + e] = a[e];
  __syncthreads();
  float ssum = 0.f;
#pragma unroll
  for (int g = 0; g < 8; ++g) ssum += red[g][tid];
  atomicAdd(&cp[cb * 256 + tid], ssum);
}

// ---------------------------------------------------------------------------
// One matvec phase. 1024 blocks x 256 thr; block owns cols j0..j0+3.
// Wave w covers rows [w*1024, (w+1)*1024) (split-K), x slice in VGPRs.
// modes: 0=P1 (u1; xout=sig(u1+cp))
//        1=P2 (f=dot+cp; fbuf=f; xout=s0(1-s0)*f, s0=old xout)
//        2=P3 (du1; xout=s1(1-s1)*du1, s1=old xout)
//        3=P4 (df; rk+=df^2; RK bookkeeping; xout=sig(ystage_next))
// ---------------------------------------------------------------------------
__global__ __launch_bounds__(TPB) void k_phase(
    int mode,
    const unsigned short* __restrict__ Wt,
    const float* __restrict__ T,
    const float* __restrict__ cp,
    const float* __restrict__ xin,
    float* __restrict__ xout,
    float* __restrict__ fbuf,
    const float* __restrict__ tptr,
    float* __restrict__ ycur,
    float* __restrict__ ksum,
    float* __restrict__ rk,
    int rkIdx, int s, float csvn, float tA, float tB) {
  __shared__ unsigned short wlds[4][4096];   // 32 KB
  __shared__ float red2[16];
  const int tid = threadIdx.x;
  const int w = tid >> 6, l = tid & 63;
  const int j0 = blockIdx.x * 4;
  const int rbase = (w << 10) + (l << 3);    // this lane's first row

  // Async-stage this wave's 1024-row slice of 4 columns (8 x 1KB DMA).
#pragma unroll
  for (int cc = 0; cc < 4; ++cc) {
#pragma unroll
    for (int k = 0; k < 2; ++k) {
      const unsigned short* g =
          Wt + ((size_t)(j0 + cc) << 12) + (w << 10) + (k << 9) + (l << 3);
      load16(g, &wlds[cc][(w << 10) + (k << 9)]);
    }
  }
  // x slice into VGPRs (rows rbase.. and rbase+512..).
  float xa[2][8];
#pragma unroll
  for (int p = 0; p < 2; ++p) {
    const float4 a = *reinterpret_cast<const float4*>(xin + rbase + (p << 9));
    const float4 b = *reinterpret_cast<const float4*>(xin + rbase + (p << 9) + 4);
    xa[p][0] = a.x; xa[p][1] = a.y; xa[p][2] = a.z; xa[p][3] = a.w;
    xa[p][4] = b.x; xa[p][5] = b.y; xa[p][6] = b.z; xa[p][7] = b.w;
  }
  __syncthreads();   // drains vmcnt (DMA + x loads) then barrier

  float acc[4] = {0.f, 0.f, 0.f, 0.f};
#pragma unroll
  for (int cc = 0; cc < 4; ++cc) {
#pragma unroll
    for (int p = 0; p < 2; ++p) {
      const us8 wv = *reinterpret_cast<const us8*>(&wlds[cc][rbase + (p << 9)]);
#pragma unroll
      for (int e = 0; e < 8; ++e)
        acc[cc] = fmaf(bf2f(wv[e]), xa[p][e], acc[cc]);
    }
  }
#pragma unroll
  for (int cc = 0; cc < 4; ++cc) {
#pragma unroll
    for (int o = 32; o >= 1; o >>= 1) acc[cc] += __shfl_down(acc[cc], o);
  }
  if (l == 0) {
#pragma unroll
    for (int cc = 0; cc < 4; ++cc) red2[w * 4 + cc] = acc[cc];
  }
  __syncthreads();

  if (tid < 4) {                              // lanes 0..3 of wave 0
    const int j = j0 + tid;
    const float dot = red2[tid] + red2[4 + tid] + red2[8 + tid] + red2[12 + tid];
    const float dt = tptr[0] * (1.0f / STEPS);
    const float tcoef = fmaf(tA, dt, tB);
    const float a = fmaf(tcoef, T[j], dot);
    if (mode == 0) {
      xout[j] = sigf(a + cp[j]);
    } else if (mode == 1) {
      const float fv = a + cp[j];
      fbuf[j] = fv;
      const float s0 = xout[j];               // = sig(ystage), P1's input
      xout[j] = s0 * (1.f - s0) * fv;
    } else if (mode == 2) {
      const float s1 = xout[j];               // = sig(u1), P2's input
      xout[j] = s1 * (1.f - s1) * a;
    } else {
      float v = a * a;
      const float fc = fbuf[j];
      float y = ycur[j];
      if (s == 0)      ksum[j] = fc;
      else if (s < 3)  ksum[j] = fmaf(2.f, fc, ksum[j]);
      else { y = fmaf(dt * (1.f / 6.f), ksum[j] + fc, y); ycur[j] = y; }
      xout[j] = sigf(fmaf(csvn * dt, fc, y)); // next stage's x1
      v += __shfl_down(v, 2);
      v += __shfl_down(v, 1);
      if (tid == 0) atomicAdd(&rk[rkIdx], v);
    }
  }
}

// ---------------------------------------------------------------------------
// out[0..N) = ycur; out[N] = RK4-weighted integral of mean(df^2).
// ---------------------------------------------------------------------------
__global__ __launch_bounds__(128) void k_fin(const float* __restrict__ ycur,
                                             const float* __restrict__ rk,
                                             const float* __restrict__ tptr,
                                             float* __restrict__ out) {
  const int j = blockIdx.x * 128 + threadIdx.x;
  if (j < N) out[j] = ycur[j];
  if (j == 0) {
    const float dt = tptr[0] * (1.0f / STEPS);
    float r = 0.f;
    for (int st = 0; st < STEPS; ++st)
      r += rk[4 * st] + 2.f * rk[4 * st + 1] + 2.f * rk[4 * st + 2] + rk[4 * st + 3];
    out[N] = r * (dt / 6.f) * (1.0f / N);
  }
}

// ---------------------------------------------------------------------------
extern "C" void kernel_launch(void* const* d_in, const int* in_sizes, int n_in,
                              void* d_out, int out_size, void* d_ws, size_t ws_size,
                              hipStream_t stream) {
  const float* h  = (const float*)d_in[0];
  const float* t  = (const float*)d_in[1];
  const float* c  = (const float*)d_in[2];
  const float* W1 = (const float*)d_in[3];
  const float* b1 = (const float*)d_in[4];
  const float* W2 = (const float*)d_in[5];
  const float* b2 = (const float*)d_in[6];
  float* out = (float*)d_out;

  // ws: Wt1 | Wt2 (bf16 col-major, 33.55 MB each) | fp32 vectors (~300 KB).
  char* ws = (char*)d_ws;
  const size_t wb = (size_t)N * N * sizeof(unsigned short);
  unsigned short* Wt1 = (unsigned short*)ws;
  unsigned short* Wt2 = (unsigned short*)(ws + wb);
  float* fp = (float*)(ws + 2 * wb);
  float* xA   = fp;
  float* xB   = xA + N;
  float* cp1  = xB + N;
  float* cp2  = cp1 + N;
  float* fbuf = cp2 + N;
  float* ycur = fbuf + N;
  float* ksum = ycur + N;
  float* T1   = ksum + N;
  float* T2   = T1 + N;
  float* rk   = T2 + N;   // 16

  k_init<<<16, TPB, 0, stream>>>(h, W1, W2, b1, b2, ycur, cp1, cp2, xA, T1, T2, rk);
  k_conv<<<dim3(64, 64, 2), TPB, 0, stream>>>(W1, W2, Wt1, Wt2);
  k_cpart<<<dim3(16, 8, 2), TPB, 0, stream>>>(W1, W2, c, cp1, cp2);

  const float csv[4] = {0.f, 0.5f, 0.5f, 1.f};
  float* xb[2] = {xA, xB};
  int xp = 0;
  for (int i = 0; i < 16; ++i) {
    const int step = i >> 2, s = i & 3;
    const float tsv = (float)step + csv[s];
    // P1: u1 = x1@W1 + cp1 + t*T1 ; x2 = sig(u1)
    k_phase<<<1024, TPB, 0, stream>>>(0, Wt1, T1, cp1, xb[xp], xb[xp ^ 1], fbuf,
                                      t, ycur, ksum, rk, 0, s, 0.f, tsv, 0.f);
    xp ^= 1;
    // P2: f = x2@W2 + cp2 + t*T2 ; v1 = s0'(ys)*f
    k_phase<<<1024, TPB, 0, stream>>>(1, Wt2, T2, cp2, xb[xp], xb[xp ^ 1], fbuf,
                                      t, ycur, ksum, rk, 0, s, 0.f, tsv, 0.f);
    xp ^= 1;
    // P3: du1 = v1@W1 + 1*T1 ; v2 = s1'(u1)*du1
    k_phase<<<1024, TPB, 0, stream>>>(2, Wt1, T1, nullptr, xb[xp], xb[xp ^ 1], fbuf,
                                      t, ycur, ksum, rk, 0, s, 0.f, 0.f, 1.f);
    xp ^= 1;
    // P4: df = v2@W2 + 1*T2 ; rk += df^2 ; RK bookkeeping ; x1_next
    k_phase<<<1024, TPB, 0, stream>>>(3, Wt2, T2, nullptr, xb[xp], xb[xp ^ 1], fbuf,
                                      t, ycur, ksum, rk, i, s, csv[(s + 1) & 3],
                                      0.f, 1.f);
    xp ^= 1;
  }
  k_fin<<<32, 128, 0, stream>>>(ycur, rk, t, out);
}